// Round 7
// baseline (207.281 us; speedup 1.0000x reference)
//
#include <hip/hip_runtime.h>
#include <math.h>

#define D_MODEL 1024
#define NHEADS  16
#define HEADD   64
#define NFREQ   32
#define BATCH   2
#define CSEQ    2048
#define NROWS   (BATCH*CSEQ)   // 4096
#define NQKV    (3*D_MODEL)    // 3072

typedef _Float16 half8  __attribute__((ext_vector_type(8)));
typedef _Float16 half4v __attribute__((ext_vector_type(4)));
typedef float    f32x4  __attribute__((ext_vector_type(4)));

// async global->LDS, 16B per lane. dest is WAVE-UNIFORM base (HW adds lane*16).
__device__ __forceinline__ void async16(void* lds, const void* g)
{
    __builtin_amdgcn_global_load_lds((const __attribute__((address_space(1))) unsigned int*)g,
                                     (__attribute__((address_space(3))) unsigned int*)lds,
                                     16, 0, 0);
}

// ---------------------------------------------------------------------------
// cos/sin table (double precision mel to match numpy f64 -> f32 cast)
// ---------------------------------------------------------------------------
__global__ __launch_bounds__(256) void build_cs_kernel(float2* __restrict__ cs)
{
    int i = blockIdx.x * 256 + threadIdx.x;
    if (i >= CSEQ * NFREQ) return;
    int c = i >> 5, f = i & (NFREQ - 1);
    double mel_max = 2595.0 * log10(21.0);
    double step    = mel_max / (double)(NFREQ - 1);
    double freq    = 200.0 * (pow(10.0, step * (double)f / 2595.0) - 1.0) / 1000.0;
    float fr = (float)freq;
    float th = (float)c * fr;
    float s, co;
    sincosf(th, &s, &co);
    cs[i] = make_float2(co, s);
}

// ---------------------------------------------------------------------------
// bias_eff init: [bq | bkv]
// ---------------------------------------------------------------------------
__global__ __launch_bounds__(256) void bias_init_kernel(
    const float* __restrict__ bq, const float* __restrict__ bkv, float* __restrict__ be)
{
    int i = blockIdx.x * 256 + threadIdx.x;
    if (i < D_MODEL) be[i] = bq[i];
    else if (i < NQKV) be[i] = bkv[i - D_MODEL];
}

// ---------------------------------------------------------------------------
// Transpose + optional row-scale (LN gain fold) + cast fp32(R x C)->fp16(C x R),
// and optional LN-bias fold: bias_acc[n] += sum_k bfold[k]*W[k][n] (atomicAdd).
// ---------------------------------------------------------------------------
__global__ __launch_bounds__(256) void transpose_fold_kernel(
    const float* __restrict__ in, _Float16* __restrict__ out, int R, int C,
    int rowoff, const float* __restrict__ scale,
    const float* __restrict__ bfold, float* __restrict__ bias_acc)
{
    __shared__ float t[32][33];
    __shared__ float part[4][32];
    int bx = blockIdx.x * 32;   // C (n) offset
    int by = blockIdx.y * 32;   // R (k) offset
    int tx = threadIdx.x, ty = threadIdx.y;
    #pragma unroll
    for (int i = ty; i < 32; i += 8)
        t[i][tx] = in[(size_t)(by + i) * C + bx + tx];
    __syncthreads();
    float sc = scale ? scale[by + tx] : 1.f;
    #pragma unroll
    for (int i = ty; i < 32; i += 8)
        out[(size_t)(rowoff + bx + i) * R + by + tx] = (_Float16)(t[tx][i] * sc);
    if (bfold) {
        float p = 0.f;
        #pragma unroll
        for (int i = ty; i < 32; i += 8)
            p += bfold[by + i] * t[i][tx];
        p += __shfl_xor(p, 32);           // combine ty pairs within wave
        if ((ty & 1) == 0) part[ty >> 1][tx] = p;
        __syncthreads();
        if (ty == 0)
            atomicAdd(&bias_acc[rowoff + bx + tx],
                      part[0][tx] + part[1][tx] + part[2][tx] + part[3][tx]);
    }
}

// ---------------------------------------------------------------------------
// LN stats + radius; writes xn fp16 (normalized, un-scaled: gains folded in W)
// ---------------------------------------------------------------------------
__global__ __launch_bounds__(256) void ln_radius_kernel(
    const float* __restrict__ x,
    const float* __restrict__ Wr,  const float* __restrict__ br,
    _Float16* __restrict__ xn, float* __restrict__ radius)
{
    int row = blockIdx.x;
    int tid = threadIdx.x;
    float4 xv = ((const float4*)(x + (size_t)row * D_MODEL))[tid];
    float4 wv = ((const float4*)Wr)[tid];
    float s  = xv.x + xv.y + xv.z + xv.w;
    float ss = xv.x*xv.x + xv.y*xv.y + xv.z*xv.z + xv.w*xv.w;
    float dr = xv.x*wv.x + xv.y*wv.y + xv.z*wv.z + xv.w*wv.w;
    #pragma unroll
    for (int off = 1; off < 64; off <<= 1) {
        s  += __shfl_xor(s, off);
        ss += __shfl_xor(ss, off);
        dr += __shfl_xor(dr, off);
    }
    __shared__ float red[3][4];
    int w = tid >> 6, lane = tid & 63;
    if (lane == 0) { red[0][w] = s; red[1][w] = ss; red[2][w] = dr; }
    __syncthreads();
    s  = red[0][0] + red[0][1] + red[0][2] + red[0][3];
    ss = red[1][0] + red[1][1] + red[1][2] + red[1][3];
    float mean = s * (1.f / D_MODEL);
    float var  = ss * (1.f / D_MODEL) - mean * mean;
    float rinv = rsqrtf(var + 1e-5f);
    half4v o4 = { (_Float16)((xv.x - mean) * rinv), (_Float16)((xv.y - mean) * rinv),
                  (_Float16)((xv.z - mean) * rinv), (_Float16)((xv.w - mean) * rinv) };
    *(half4v*)&xn[(size_t)row * D_MODEL + tid * 4] = o4;
    if (tid == 0) {
        float drt = red[2][0] + red[2][1] + red[2][2] + red[2][3];
        float p = (drt + br[0]) * 0.01f;
        radius[row] = fminf(fmaxf(p, 0.5f), 2.0f);
    }
}

// ---------------------------------------------------------------------------
// GEMM core: 128x128 tile, BK=32 double-buffered (16KB LDS total),
// global_load_lds staging, 1 barrier per K-step, 16 MFMA per step.
// ---------------------------------------------------------------------------
__device__ __forceinline__ void gemm_core32(
    const _Float16* __restrict__ A, const _Float16* __restrict__ B,
    int bm, int bn, int K, _Float16* As, _Float16* Bs, f32x4 (*acc)[4])
{
    int tid = threadIdx.x, lane = tid & 63, w = tid >> 6;
    int wm = w >> 1, wn = w & 1;
    int l15 = lane & 15, lg = lane >> 4;
    int sr  = lane >> 2;      // 0..15 row within 16-row segment
    int sch = lane & 3;       // 16B chunk within 64B row

    auto stage = [&](int buf, int k0) {
        #pragma unroll
        for (int i = 0; i < 2; ++i) {
            int seg = w * 2 + i;                 // 0..7, 16 rows each
            int row = seg * 16 + sr;
            async16(&As[buf * 4096 + seg * 512], &A[(size_t)(bm + row) * K + k0 + sch * 8]);
            async16(&Bs[buf * 4096 + seg * 512], &B[(size_t)(bn + row) * K + k0 + sch * 8]);
        }
    };

    stage(0, 0);
    __syncthreads();
    int cur = 0;
    for (int k0 = 0; k0 < K; k0 += 32) {
        if (k0 + 32 < K) stage(cur ^ 1, k0 + 32);
        half8 af[4], bf[4];
        #pragma unroll
        for (int m = 0; m < 4; ++m)
            af[m] = *(const half8*)&As[cur * 4096 + (wm * 64 + m * 16 + l15) * 32 + lg * 8];
        #pragma unroll
        for (int n = 0; n < 4; ++n)
            bf[n] = *(const half8*)&Bs[cur * 4096 + (wn * 64 + n * 16 + l15) * 32 + lg * 8];
        #pragma unroll
        for (int m = 0; m < 4; ++m)
            #pragma unroll
            for (int n = 0; n < 4; ++n)
                acc[m][n] = __builtin_amdgcn_mfma_f32_16x16x32_f16(af[m], bf[n], acc[m][n], 0, 0, 0);
        __syncthreads();
        cur ^= 1;
    }
}

// ---------------------------------------------------------------------------
// Fused qkv GEMM: xn (M=4096 x K=1024) x WqkvT (N=3072) + bias_eff.
// q epilogue pre-scales by 0.125*log2(e) (softmax exp2 fold).
// ---------------------------------------------------------------------------
#define QSCALE 0.18033688f   // 0.125 * log2(e)

__global__ __launch_bounds__(256, 4) void gemm_qkv_kernel(
    const _Float16* __restrict__ xn,  const _Float16* __restrict__ WT,
    const float* __restrict__ bias_eff,
    const float* __restrict__ radius, const float2* __restrict__ cs_tab,
    const float* __restrict__ lnh_g,  const float* __restrict__ lnh_b,
    _Float16* __restrict__ qn, _Float16* __restrict__ kn, _Float16* __restrict__ v_rm)
{
    __shared__ _Float16 As[2 * 4096];
    __shared__ _Float16 Bs[2 * 4096];
    int orig = blockIdx.x;
    int wg = (orig & 7) * 96 + (orig >> 3);   // bijective, 768 = 8*96
    int bm = (wg / 24) * 128;
    int bn = (wg % 24) * 128;

    f32x4 acc[4][4];
    f32x4 z = {0.f, 0.f, 0.f, 0.f};
    #pragma unroll
    for (int m = 0; m < 4; ++m)
        #pragma unroll
        for (int n = 0; n < 4; ++n) acc[m][n] = z;

    gemm_core32(xn, WT, bm, bn, D_MODEL, As, Bs, acc);

    int tid = threadIdx.x, lane = tid & 63, w = tid >> 6;
    int wm = w >> 1, wn = w & 1;
    int l15 = lane & 15, lg = lane >> 4;
    int colbase = bn + wn * 64;

    float bb4[4];
    #pragma unroll
    for (int n = 0; n < 4; ++n) bb4[n] = bias_eff[colbase + n * 16 + l15];

    if (colbase >= 2 * D_MODEL) {
        int vcolb = colbase - 2 * D_MODEL;
        #pragma unroll
        for (int m = 0; m < 4; ++m)
            #pragma unroll
            for (int r = 0; r < 4; ++r) {
                int row = bm + wm * 64 + m * 16 + lg * 4 + r;
                #pragma unroll
                for (int n = 0; n < 4; ++n)
                    v_rm[(size_t)row * D_MODEL + vcolb + n * 16 + l15] =
                        (_Float16)(acc[m][n][r] + bb4[n]);
            }
        return;
    }

    bool isq = colbase < D_MODEL;
    int h = (colbase & (D_MODEL - 1)) >> 6;
    _Float16* dst = isq ? qn : kn;
    float qs = isq ? QSCALE : 1.f;
    bool im = (l15 & 1) != 0;

    float g4[4], bh4[4];
    #pragma unroll
    for (int n = 0; n < 4; ++n) {
        g4[n]  = lnh_g[n * 16 + l15];
        bh4[n] = lnh_b[n * 16 + l15];
    }

    #pragma unroll
    for (int m = 0; m < 4; ++m)
        #pragma unroll
        for (int r = 0; r < 4; ++r) {
            int row = bm + wm * 64 + m * 16 + lg * 4 + r;
            int b = row >> 11, c = row & (CSEQ - 1);
            float rr = radius[row];
            float vals[4];
            float s = 0.f, ss = 0.f;
            #pragma unroll
            for (int n = 0; n < 4; ++n) {
                float v0 = acc[m][n][r] + bb4[n];
                float pr = __shfl_xor(v0, 1);
                float2 cs = cs_tab[c * NFREQ + ((n * 16 + l15) >> 1)];
                float xr_ = im ? pr : v0;
                float xi_ = im ? v0 : pr;
                float rot = im ? rr * (xr_ * cs.y + xi_ * cs.x)
                               : rr * (xr_ * cs.x - xi_ * cs.y);
                vals[n] = rot;
                s += rot; ss += rot * rot;
            }
            #pragma unroll
            for (int off = 1; off < 16; off <<= 1) {
                s  += __shfl_xor(s, off);
                ss += __shfl_xor(ss, off);
            }
            float mean = s * (1.f / 64.f);
            float var  = ss * (1.f / 64.f) - mean * mean;
            float ri   = rsqrtf(var + 1e-5f);
            size_t base = ((size_t)(b * NHEADS + h) * CSEQ + c) * HEADD;
            #pragma unroll
            for (int n = 0; n < 4; ++n) {
                float o = ((vals[n] - mean) * ri * g4[n] + bh4[n]) * qs;
                dst[base + n * 16 + l15] = (_Float16)o;
            }
        }
}

// ---------------------------------------------------------------------------
// Output GEMM
// ---------------------------------------------------------------------------
__global__ __launch_bounds__(256, 4) void gemm_out_kernel(
    const _Float16* __restrict__ A, const _Float16* __restrict__ BT,
    const float* __restrict__ bias, float* __restrict__ C)
{
    __shared__ _Float16 As[2 * 4096];
    __shared__ _Float16 Bs[2 * 4096];
    int orig = blockIdx.x;
    int wg = (orig & 7) * 32 + (orig >> 3);   // 256 = 8*32
    int bm = (wg >> 3) * 128;
    int bn = (wg & 7) * 128;

    f32x4 acc[4][4];
    f32x4 z = {0.f, 0.f, 0.f, 0.f};
    #pragma unroll
    for (int m = 0; m < 4; ++m)
        #pragma unroll
        for (int n = 0; n < 4; ++n) acc[m][n] = z;

    gemm_core32(A, BT, bm, bn, D_MODEL, As, Bs, acc);

    int tid = threadIdx.x, lane = tid & 63, w = tid >> 6;
    int wm = w >> 1, wn = w & 1;
    int l15 = lane & 15, lg = lane >> 4;
    #pragma unroll
    for (int m = 0; m < 4; ++m) {
        int row = bm + wm * 64 + m * 16 + lg * 4;
        #pragma unroll
        for (int n = 0; n < 4; ++n) {
            int col = bn + wn * 64 + n * 16 + l15;
            float bb = bias[col];
            #pragma unroll
            for (int r = 0; r < 4; ++r)
                C[(size_t)(row + r) * D_MODEL + col] = acc[m][n][r] + bb;
        }
    }
}

// ---------------------------------------------------------------------------
// V row-major fp16 -> vT (B,H,HD,C) fp16
// ---------------------------------------------------------------------------
__global__ __launch_bounds__(256) void v_transpose_f16(
    const _Float16* __restrict__ v_rm, _Float16* __restrict__ vT)
{
    int bh = blockIdx.x >> 5;
    int c0 = (blockIdx.x & 31) * 64;
    int b = bh >> 4, h = bh & 15;
    __shared__ _Float16 t[64][68];
    int tid = threadIdx.x;
    int dcol = tid & 63, quarter = tid >> 6;
    for (int c = quarter; c < 64; c += 4)
        t[c][dcol] = v_rm[(size_t)(b * CSEQ + c0 + c) * D_MODEL + h * HEADD + dcol];
    __syncthreads();
    for (int d = quarter; d < 64; d += 4)
        vT[(size_t)(bh * HEADD + d) * CSEQ + c0 + dcol] = t[dcol][d];
}

// ---------------------------------------------------------------------------
// Flash attention v4: split-K flash. Block = 64 q, 4 waves; each wave owns a
// 16-key slice of every 64-key tile for all 64 q. Fixed-max softmax
// (|S|<=8 hard bound from head-LN): p = exp2(S*log2e - 8*log2e), the constant
// folded into the MFMA C-initializer. P feeds PV 16x16x16 MFMA directly from
// registers (zero P LDS traffic). Epilogue: LDS tree-combine of 4 partials.
// ---------------------------------------------------------------------------
#define KVB 64
#define NT  (CSEQ / KVB)
#define C8L2E 11.541560f      // 8 * log2(e)
#define ORED_STRIDE 68

__global__ __launch_bounds__(256, 4) void attn_kernel(
    const _Float16* __restrict__ qn, const _Float16* __restrict__ kn,
    const _Float16* __restrict__ vT, _Float16* __restrict__ o)
{
    // contiguous K/V double-buffer region, reused as f32 Ored in epilogue
    __shared__ _Float16 kv_lds[4 * 4096];     // 32 KB
    __shared__ float lbuf[4][64];             // 1 KB
    _Float16* Ksp = kv_lds;                   // [2][4096]
    _Float16* Vsp = kv_lds + 2 * 4096;        // [2][4096]

    int tid = threadIdx.x, lane = tid & 63, w = tid >> 6;
    int l15 = lane & 15, lg = lane >> 4;

    int orig = blockIdx.x;
    int wg   = (orig & 7) * 128 + (orig >> 3);   // bijective, 1024 = 8*128
    int bh   = wg >> 5;
    int qc   = wg & 31;
    int q0   = qc * 64;

    const _Float16* qh = qn + (size_t)bh * CSEQ * HEADD;
    const _Float16* kh = kn + (size_t)bh * CSEQ * HEADD;
    const _Float16* vh = vT + (size_t)bh * HEADD * CSEQ;

    // Q fragments: all 64 q rows (4 qblk), full HD (2 ks)
    half8 aq[4][2];
    #pragma unroll
    for (int qb = 0; qb < 4; ++qb)
        #pragma unroll
        for (int ks = 0; ks < 2; ++ks)
            aq[qb][ks] = *(const half8*)&qh[(size_t)(q0 + qb * 16 + l15) * HEADD + ks * 32 + lg * 8];

    f32x4 z = {0.f, 0.f, 0.f, 0.f};
    f32x4 oacc[4][4];            // [qblk][dblk]
    #pragma unroll
    for (int qb = 0; qb < 4; ++qb)
        #pragma unroll
        for (int db = 0; db < 4; ++db) oacc[qb][db] = z;
    float lsum[4] = {0.f, 0.f, 0.f, 0.f};

    int srow_in = lane >> 3;
    int csrc    = (lane & 7) ^ srow_in;          // XOR pre-swizzled source chunk
    int l7      = l15 & 7;

    auto stage = [&](int buf, int kt) {
        int k0 = kt * KVB;
        #pragma unroll
        for (int i = 0; i < 2; ++i) {
            int seg = w * 2 + i;
            int r = seg * 8 + srow_in;
            async16(&Ksp[buf * 4096 + seg * 512], &kh[(size_t)(k0 + r) * HEADD + csrc * 8]);
            async16(&Vsp[buf * 4096 + seg * 512], &vh[(size_t)r * CSEQ + k0 + csrc * 8]);
        }
    };

    stage(0, 0);
    __syncthreads();
    int cur = 0;

    // wave's k-slice rows within tile: w*16 + l15 ; chunk swizzle key = l15&7
    int krow = w * 16 + l15;
    int vchunk = w * 2 + (lg >> 1);              // 16B chunk of wave's k-slice
    int vbyteoff = (lg & 1) * 4;                 // halves within chunk

    for (int kt = 0; kt < NT; ++kt) {
        if (kt + 1 < NT) stage(cur ^ 1, kt + 1);

        // K fragments for wave's 16 keys (read once, reused across 4 qblk)
        half8 ak0 = *(const half8*)&Ksp[cur * 4096 + krow * 64 + ((0 * 4 + lg) ^ l7) * 8];
        half8 ak1 = *(const half8*)&Ksp[cur * 4096 + krow * 64 + ((1 * 4 + lg) ^ l7) * 8];

        // S^T + fixed-max softmax + P-frag build (all in registers)
        half4v ap[4];
        #pragma unroll
        for (int qb = 0; qb < 4; ++qb) {
            f32x4 st = {-C8L2E, -C8L2E, -C8L2E, -C8L2E};
            st = __builtin_amdgcn_mfma_f32_16x16x32_f16(ak0, aq[qb][0], st, 0, 0, 0);
            st = __builtin_amdgcn_mfma_f32_16x16x32_f16(ak1, aq[qb][1], st, 0, 0, 0);
            float p0 = exp2f(st[0]), p1 = exp2f(st[1]);
            float p2 = exp2f(st[2]), p3 = exp2f(st[3]);
            lsum[qb] += (p0 + p1) + (p2 + p3);
            half4v pk = { (_Float16)p0, (_Float16)p1, (_Float16)p2, (_Float16)p3 };
            ap[qb] = pk;
        }

        // PV: 16x16x16 MFMA, contraction over wave's 16 keys
        #pragma unroll
        for (int db = 0; db < 4; ++db) {
            int vrow = db * 16 + l15;
            half4v bv = *(const half4v*)&Vsp[cur * 4096 + vrow * 64 +
                                             (vchunk ^ (vrow & 7)) * 8 + vbyteoff];
            #pragma unroll
            for (int qb = 0; qb < 4; ++qb)
                oacc[qb][db] = __builtin_amdgcn_mfma_f32_16x16x16f16(ap[qb], bv, oacc[qb][db], 0, 0, 0);
        }

        __syncthreads();
        cur ^= 1;
    }

    // ---- epilogue: combine 4 wave-partials (no max exchange needed) ----
    // per-wave l: reduce across lg groups
    #pragma unroll
    for (int qb = 0; qb < 4; ++qb) {
        float l = lsum[qb];
        l += __shfl_xor(l, 16);
        l += __shfl_xor(l, 32);
        lsum[qb] = l;
    }
    if (lg == 0) {
        #pragma unroll
        for (int qb = 0; qb < 4; ++qb) lbuf[w][qb * 16 + l15] = lsum[qb];
    }

    float* Ored = (float*)kv_lds;                // 64 x 68 f32 = 17.4 KB
    #pragma unroll
    for (int ph = 0; ph < 4; ++ph) {
        if (w == ph) {
            #pragma unroll
            for (int qb = 0; qb < 4; ++qb)
                #pragma unroll
                for (int db = 0; db < 4; ++db)
                    #pragma unroll
                    for (int r = 0; r < 4; ++r) {
                        int idx = (qb * 16 + lg * 4 + r) * ORED_STRIDE + db * 16 + l15;
                        if (ph == 0) Ored[idx] = oacc[qb][db][r];
                        else         Ored[idx] += oacc[qb][db][r];
                    }
        }
        __syncthreads();
    }

    // final: wave w stores q rows w*16..w*16+15
    int ql = w * 16 + (lane >> 2);
    int d0 = (lane & 3) * 16;
    float ltot = lbuf[0][ql] + lbuf[1][ql] + lbuf[2][ql] + lbuf[3][ql];
    float linv = 1.f / ltot;
    int b = bh >> 4, h = bh & 15;
    int c = q0 + ql;
    size_t base = ((size_t)b * CSEQ + c) * D_MODEL + h * HEADD + d0;
    const float4* orow = (const float4*)&Ored[ql * ORED_STRIDE + d0];
    half8 o8a, o8b;
    #pragma unroll
    for (int j = 0; j < 2; ++j) {
        float4 f = orow[j];
        o8a[j*4+0] = (_Float16)(f.x * linv); o8a[j*4+1] = (_Float16)(f.y * linv);
        o8a[j*4+2] = (_Float16)(f.z * linv); o8a[j*4+3] = (_Float16)(f.w * linv);
    }
    #pragma unroll
    for (int j = 0; j < 2; ++j) {
        float4 f = orow[2+j];
        o8b[j*4+0] = (_Float16)(f.x * linv); o8b[j*4+1] = (_Float16)(f.y * linv);
        o8b[j*4+2] = (_Float16)(f.z * linv); o8b[j*4+3] = (_Float16)(f.w * linv);
    }
    *(half8*)&o[base]     = o8a;
    *(half8*)&o[base + 8] = o8b;
}

// ---------------------------------------------------------------------------
extern "C" void kernel_launch(void* const* d_in, const int* in_sizes, int n_in,
                              void* d_out, int out_size, void* d_ws, size_t ws_size,
                              hipStream_t stream)
{
    (void)in_sizes; (void)n_in; (void)out_size; (void)ws_size;
    const float* x      = (const float*)d_in[0];
    const float* ln_q_g = (const float*)d_in[1];
    const float* ln_q_b = (const float*)d_in[2];
    const float* Wq     = (const float*)d_in[3];
    const float* bq     = (const float*)d_in[4];
    const float* ln_kv_g= (const float*)d_in[5];
    const float* ln_kv_b= (const float*)d_in[6];
    const float* Wkv    = (const float*)d_in[7];
    const float* bkv    = (const float*)d_in[8];
    const float* Wout   = (const float*)d_in[9];
    const float* bout   = (const float*)d_in[10];
    const float* lnh_g  = (const float*)d_in[11];
    const float* lnh_b  = (const float*)d_in[12];
    const float* Wr     = (const float*)d_in[13];
    const float* br     = (const float*)d_in[14];
    float* out = (float*)d_out;

    char* ws = (char*)d_ws;
    size_t off = 0;
    auto alloc = [&](size_t bytes) -> void* {
        void* p = ws + off;
        off += (bytes + 255) & ~(size_t)255;
        return p;
    };
    _Float16* WqkvT  = (_Float16*)alloc((size_t)NQKV * D_MODEL * 2);
    _Float16* WoutT  = (_Float16*)alloc((size_t)D_MODEL * D_MODEL * 2);
    float*    bias_e = (float*)   alloc((size_t)NQKV * 4);
    float*    radius = (float*)   alloc((size_t)NROWS * 4);
    float2*   cs_tab = (float2*)  alloc((size_t)CSEQ * NFREQ * 8);
    _Float16* vT     = (_Float16*)alloc((size_t)BATCH * NHEADS * HEADD * CSEQ * 2);
    _Float16* v_rm   = (_Float16*)alloc((size_t)NROWS * D_MODEL * 2);
    _Float16* xn     = (_Float16*)alloc((size_t)NROWS * D_MODEL * 2);
    _Float16* qn     = (_Float16*)alloc((size_t)NROWS * D_MODEL * 2);
    _Float16* kn     = (_Float16*)alloc((size_t)NROWS * D_MODEL * 2);
    _Float16* o_h    = (_Float16*)alloc((size_t)NROWS * D_MODEL * 2);

    hipLaunchKernelGGL(bias_init_kernel, dim3(NQKV / 256), dim3(256), 0, stream, bq, bkv, bias_e);
    hipLaunchKernelGGL(build_cs_kernel, dim3(CSEQ * NFREQ / 256), dim3(256), 0, stream, cs_tab);
    hipLaunchKernelGGL(transpose_fold_kernel, dim3(D_MODEL/32, D_MODEL/32), dim3(32, 8), 0, stream,
                       Wq, WqkvT, D_MODEL, D_MODEL, 0, ln_q_g, ln_q_b, bias_e);
    hipLaunchKernelGGL(transpose_fold_kernel, dim3(2*D_MODEL/32, D_MODEL/32), dim3(32, 8), 0, stream,
                       Wkv, WqkvT, D_MODEL, 2*D_MODEL, D_MODEL, ln_kv_g, ln_kv_b, bias_e);
    hipLaunchKernelGGL(transpose_fold_kernel, dim3(D_MODEL/32, D_MODEL/32), dim3(32, 8), 0, stream,
                       Wout, WoutT, D_MODEL, D_MODEL, 0, (const float*)nullptr,
                       (const float*)nullptr, (float*)nullptr);
    hipLaunchKernelGGL(ln_radius_kernel, dim3(NROWS), dim3(256), 0, stream,
                       x, Wr, br, xn, radius);
    hipLaunchKernelGGL(gemm_qkv_kernel, dim3(768), dim3(256), 0, stream,
                       xn, WqkvT, bias_e, radius, cs_tab, lnh_g, lnh_b, qn, kn, v_rm);
    hipLaunchKernelGGL(v_transpose_f16, dim3(BATCH*NHEADS*CSEQ/64), dim3(256), 0, stream,
                       v_rm, vT);
    hipLaunchKernelGGL(attn_kernel, dim3(BATCH*NHEADS*CSEQ/64), dim3(256), 0, stream,
                       qn, kn, vT, o_h);
    hipLaunchKernelGGL(gemm_out_kernel, dim3(256), dim3(256), 0, stream,
                       o_h, WoutT, bout, out);
}

// Round 8
// 160.441 us; speedup vs baseline: 1.2919x; 1.2919x over previous
//
#include <hip/hip_runtime.h>
#include <math.h>

#define D_MODEL 1024
#define NHEADS  16
#define HEADD   64
#define NFREQ   32
#define BATCH   2
#define CSEQ    2048
#define NROWS   (BATCH*CSEQ)   // 4096
#define NQKV    (3*D_MODEL)    // 3072

typedef _Float16 half8  __attribute__((ext_vector_type(8)));
typedef _Float16 half4v __attribute__((ext_vector_type(4)));
typedef float    f32x4  __attribute__((ext_vector_type(4)));

// async global->LDS, 16B per lane. dest is WAVE-UNIFORM base (HW adds lane*16).
__device__ __forceinline__ void async16(void* lds, const void* g)
{
    __builtin_amdgcn_global_load_lds((const __attribute__((address_space(1))) unsigned int*)g,
                                     (__attribute__((address_space(3))) unsigned int*)lds,
                                     16, 0, 0);
}

// ---------------------------------------------------------------------------
// cos/sin table (double precision mel to match numpy f64 -> f32 cast)
// ---------------------------------------------------------------------------
__global__ __launch_bounds__(256) void build_cs_kernel(float2* __restrict__ cs)
{
    int i = blockIdx.x * 256 + threadIdx.x;
    if (i >= CSEQ * NFREQ) return;
    int c = i >> 5, f = i & (NFREQ - 1);
    double mel_max = 2595.0 * log10(21.0);
    double step    = mel_max / (double)(NFREQ - 1);
    double freq    = 200.0 * (pow(10.0, step * (double)f / 2595.0) - 1.0) / 1000.0;
    float fr = (float)freq;
    float th = (float)c * fr;
    float s, co;
    sincosf(th, &s, &co);
    cs[i] = make_float2(co, s);
}

// ---------------------------------------------------------------------------
// bias_eff init: [bq | bkv]
// ---------------------------------------------------------------------------
__global__ __launch_bounds__(256) void bias_init_kernel(
    const float* __restrict__ bq, const float* __restrict__ bkv, float* __restrict__ be)
{
    int i = blockIdx.x * 256 + threadIdx.x;
    if (i < D_MODEL) be[i] = bq[i];
    else if (i < NQKV) be[i] = bkv[i - D_MODEL];
}

// ---------------------------------------------------------------------------
// Transpose + optional row-scale (LN gain fold) + cast fp32(R x C)->fp16(C x R),
// and optional LN-bias fold: bias_acc[n] += sum_k bfold[k]*W[k][n] (atomicAdd).
// ---------------------------------------------------------------------------
__global__ __launch_bounds__(256) void transpose_fold_kernel(
    const float* __restrict__ in, _Float16* __restrict__ out, int R, int C,
    int rowoff, const float* __restrict__ scale,
    const float* __restrict__ bfold, float* __restrict__ bias_acc)
{
    __shared__ float t[32][33];
    __shared__ float part[4][32];
    int bx = blockIdx.x * 32;   // C (n) offset
    int by = blockIdx.y * 32;   // R (k) offset
    int tx = threadIdx.x, ty = threadIdx.y;
    #pragma unroll
    for (int i = ty; i < 32; i += 8)
        t[i][tx] = in[(size_t)(by + i) * C + bx + tx];
    __syncthreads();
    float sc = scale ? scale[by + tx] : 1.f;
    #pragma unroll
    for (int i = ty; i < 32; i += 8)
        out[(size_t)(rowoff + bx + i) * R + by + tx] = (_Float16)(t[tx][i] * sc);
    if (bfold) {
        float p = 0.f;
        #pragma unroll
        for (int i = ty; i < 32; i += 8)
            p += bfold[by + i] * t[i][tx];
        p += __shfl_xor(p, 32);           // combine ty pairs within wave
        if ((ty & 1) == 0) part[ty >> 1][tx] = p;
        __syncthreads();
        if (ty == 0)
            atomicAdd(&bias_acc[rowoff + bx + tx],
                      part[0][tx] + part[1][tx] + part[2][tx] + part[3][tx]);
    }
}

// ---------------------------------------------------------------------------
// LN stats + radius; writes xn fp16 (normalized, un-scaled: gains folded in W)
// ---------------------------------------------------------------------------
__global__ __launch_bounds__(256) void ln_radius_kernel(
    const float* __restrict__ x,
    const float* __restrict__ Wr,  const float* __restrict__ br,
    _Float16* __restrict__ xn, float* __restrict__ radius)
{
    int row = blockIdx.x;
    int tid = threadIdx.x;
    float4 xv = ((const float4*)(x + (size_t)row * D_MODEL))[tid];
    float4 wv = ((const float4*)Wr)[tid];
    float s  = xv.x + xv.y + xv.z + xv.w;
    float ss = xv.x*xv.x + xv.y*xv.y + xv.z*xv.z + xv.w*xv.w;
    float dr = xv.x*wv.x + xv.y*wv.y + xv.z*wv.z + xv.w*wv.w;
    #pragma unroll
    for (int off = 1; off < 64; off <<= 1) {
        s  += __shfl_xor(s, off);
        ss += __shfl_xor(ss, off);
        dr += __shfl_xor(dr, off);
    }
    __shared__ float red[3][4];
    int w = tid >> 6, lane = tid & 63;
    if (lane == 0) { red[0][w] = s; red[1][w] = ss; red[2][w] = dr; }
    __syncthreads();
    s  = red[0][0] + red[0][1] + red[0][2] + red[0][3];
    ss = red[1][0] + red[1][1] + red[1][2] + red[1][3];
    float mean = s * (1.f / D_MODEL);
    float var  = ss * (1.f / D_MODEL) - mean * mean;
    float rinv = rsqrtf(var + 1e-5f);
    half4v o4 = { (_Float16)((xv.x - mean) * rinv), (_Float16)((xv.y - mean) * rinv),
                  (_Float16)((xv.z - mean) * rinv), (_Float16)((xv.w - mean) * rinv) };
    *(half4v*)&xn[(size_t)row * D_MODEL + tid * 4] = o4;
    if (tid == 0) {
        float drt = red[2][0] + red[2][1] + red[2][2] + red[2][3];
        float p = (drt + br[0]) * 0.01f;
        radius[row] = fminf(fmaxf(p, 0.5f), 2.0f);
    }
}

// ---------------------------------------------------------------------------
// GEMM core: 128x128 tile, BK=32 double-buffered (16KB LDS total),
// global_load_lds staging, 1 barrier per K-step, 16 MFMA per step.
// ---------------------------------------------------------------------------
__device__ __forceinline__ void gemm_core32(
    const _Float16* __restrict__ A, const _Float16* __restrict__ B,
    int bm, int bn, int K, _Float16* As, _Float16* Bs, f32x4 (*acc)[4])
{
    int tid = threadIdx.x, lane = tid & 63, w = tid >> 6;
    int wm = w >> 1, wn = w & 1;
    int l15 = lane & 15, lg = lane >> 4;
    int sr  = lane >> 2;      // 0..15 row within 16-row segment
    int sch = lane & 3;       // 16B chunk within 64B row

    auto stage = [&](int buf, int k0) {
        #pragma unroll
        for (int i = 0; i < 2; ++i) {
            int seg = w * 2 + i;                 // 0..7, 16 rows each
            int row = seg * 16 + sr;
            async16(&As[buf * 4096 + seg * 512], &A[(size_t)(bm + row) * K + k0 + sch * 8]);
            async16(&Bs[buf * 4096 + seg * 512], &B[(size_t)(bn + row) * K + k0 + sch * 8]);
        }
    };

    stage(0, 0);
    __syncthreads();
    int cur = 0;
    for (int k0 = 0; k0 < K; k0 += 32) {
        if (k0 + 32 < K) stage(cur ^ 1, k0 + 32);
        half8 af[4], bf[4];
        #pragma unroll
        for (int m = 0; m < 4; ++m)
            af[m] = *(const half8*)&As[cur * 4096 + (wm * 64 + m * 16 + l15) * 32 + lg * 8];
        #pragma unroll
        for (int n = 0; n < 4; ++n)
            bf[n] = *(const half8*)&Bs[cur * 4096 + (wn * 64 + n * 16 + l15) * 32 + lg * 8];
        #pragma unroll
        for (int m = 0; m < 4; ++m)
            #pragma unroll
            for (int n = 0; n < 4; ++n)
                acc[m][n] = __builtin_amdgcn_mfma_f32_16x16x32_f16(af[m], bf[n], acc[m][n], 0, 0, 0);
        __syncthreads();
        cur ^= 1;
    }
}

// ---------------------------------------------------------------------------
// Fused qkv GEMM: xn (M=4096 x K=1024) x WqkvT (N=3072) + bias_eff.
// q epilogue pre-scales by 0.125*log2(e) (softmax exp2 fold).
// ---------------------------------------------------------------------------
#define QSCALE 0.18033688f   // 0.125 * log2(e)

__global__ __launch_bounds__(256, 4) void gemm_qkv_kernel(
    const _Float16* __restrict__ xn,  const _Float16* __restrict__ WT,
    const float* __restrict__ bias_eff,
    const float* __restrict__ radius, const float2* __restrict__ cs_tab,
    const float* __restrict__ lnh_g,  const float* __restrict__ lnh_b,
    _Float16* __restrict__ qn, _Float16* __restrict__ kn, _Float16* __restrict__ v_rm)
{
    __shared__ _Float16 As[2 * 4096];
    __shared__ _Float16 Bs[2 * 4096];
    int orig = blockIdx.x;
    int wg = (orig & 7) * 96 + (orig >> 3);   // bijective, 768 = 8*96
    int bm = (wg / 24) * 128;
    int bn = (wg % 24) * 128;

    f32x4 acc[4][4];
    f32x4 z = {0.f, 0.f, 0.f, 0.f};
    #pragma unroll
    for (int m = 0; m < 4; ++m)
        #pragma unroll
        for (int n = 0; n < 4; ++n) acc[m][n] = z;

    gemm_core32(xn, WT, bm, bn, D_MODEL, As, Bs, acc);

    int tid = threadIdx.x, lane = tid & 63, w = tid >> 6;
    int wm = w >> 1, wn = w & 1;
    int l15 = lane & 15, lg = lane >> 4;
    int colbase = bn + wn * 64;

    float bb4[4];
    #pragma unroll
    for (int n = 0; n < 4; ++n) bb4[n] = bias_eff[colbase + n * 16 + l15];

    if (colbase >= 2 * D_MODEL) {
        int vcolb = colbase - 2 * D_MODEL;
        #pragma unroll
        for (int m = 0; m < 4; ++m)
            #pragma unroll
            for (int r = 0; r < 4; ++r) {
                int row = bm + wm * 64 + m * 16 + lg * 4 + r;
                #pragma unroll
                for (int n = 0; n < 4; ++n)
                    v_rm[(size_t)row * D_MODEL + vcolb + n * 16 + l15] =
                        (_Float16)(acc[m][n][r] + bb4[n]);
            }
        return;
    }

    bool isq = colbase < D_MODEL;
    int h = (colbase & (D_MODEL - 1)) >> 6;
    _Float16* dst = isq ? qn : kn;
    float qs = isq ? QSCALE : 1.f;
    bool im = (l15 & 1) != 0;

    float g4[4], bh4[4];
    #pragma unroll
    for (int n = 0; n < 4; ++n) {
        g4[n]  = lnh_g[n * 16 + l15];
        bh4[n] = lnh_b[n * 16 + l15];
    }

    #pragma unroll
    for (int m = 0; m < 4; ++m)
        #pragma unroll
        for (int r = 0; r < 4; ++r) {
            int row = bm + wm * 64 + m * 16 + lg * 4 + r;
            int b = row >> 11, c = row & (CSEQ - 1);
            float rr = radius[row];
            float vals[4];
            float s = 0.f, ss = 0.f;
            #pragma unroll
            for (int n = 0; n < 4; ++n) {
                float v0 = acc[m][n][r] + bb4[n];
                float pr = __shfl_xor(v0, 1);
                float2 cs = cs_tab[c * NFREQ + ((n * 16 + l15) >> 1)];
                float xr_ = im ? pr : v0;
                float xi_ = im ? v0 : pr;
                float rot = im ? rr * (xr_ * cs.y + xi_ * cs.x)
                               : rr * (xr_ * cs.x - xi_ * cs.y);
                vals[n] = rot;
                s += rot; ss += rot * rot;
            }
            #pragma unroll
            for (int off = 1; off < 16; off <<= 1) {
                s  += __shfl_xor(s, off);
                ss += __shfl_xor(ss, off);
            }
            float mean = s * (1.f / 64.f);
            float var  = ss * (1.f / 64.f) - mean * mean;
            float ri   = rsqrtf(var + 1e-5f);
            size_t base = ((size_t)(b * NHEADS + h) * CSEQ + c) * HEADD;
            #pragma unroll
            for (int n = 0; n < 4; ++n) {
                float o = ((vals[n] - mean) * ri * g4[n] + bh4[n]) * qs;
                dst[base + n * 16 + l15] = (_Float16)o;
            }
        }
}

// ---------------------------------------------------------------------------
// Output GEMM
// ---------------------------------------------------------------------------
__global__ __launch_bounds__(256, 4) void gemm_out_kernel(
    const _Float16* __restrict__ A, const _Float16* __restrict__ BT,
    const float* __restrict__ bias, float* __restrict__ C)
{
    __shared__ _Float16 As[2 * 4096];
    __shared__ _Float16 Bs[2 * 4096];
    int orig = blockIdx.x;
    int wg = (orig & 7) * 32 + (orig >> 3);   // 256 = 8*32
    int bm = (wg >> 3) * 128;
    int bn = (wg & 7) * 128;

    f32x4 acc[4][4];
    f32x4 z = {0.f, 0.f, 0.f, 0.f};
    #pragma unroll
    for (int m = 0; m < 4; ++m)
        #pragma unroll
        for (int n = 0; n < 4; ++n) acc[m][n] = z;

    gemm_core32(A, BT, bm, bn, D_MODEL, As, Bs, acc);

    int tid = threadIdx.x, lane = tid & 63, w = tid >> 6;
    int wm = w >> 1, wn = w & 1;
    int l15 = lane & 15, lg = lane >> 4;
    #pragma unroll
    for (int m = 0; m < 4; ++m) {
        int row = bm + wm * 64 + m * 16 + lg * 4;
        #pragma unroll
        for (int n = 0; n < 4; ++n) {
            int col = bn + wn * 64 + n * 16 + l15;
            float bb = bias[col];
            #pragma unroll
            for (int r = 0; r < 4; ++r)
                C[(size_t)(row + r) * D_MODEL + col] = acc[m][n][r] + bb;
        }
    }
}

// ---------------------------------------------------------------------------
// V row-major fp16 -> vT (B,H,HD,C) fp16
// ---------------------------------------------------------------------------
__global__ __launch_bounds__(256) void v_transpose_f16(
    const _Float16* __restrict__ v_rm, _Float16* __restrict__ vT)
{
    int bh = blockIdx.x >> 5;
    int c0 = (blockIdx.x & 31) * 64;
    int b = bh >> 4, h = bh & 15;
    __shared__ _Float16 t[64][68];
    int tid = threadIdx.x;
    int dcol = tid & 63, quarter = tid >> 6;
    for (int c = quarter; c < 64; c += 4)
        t[c][dcol] = v_rm[(size_t)(b * CSEQ + c0 + c) * D_MODEL + h * HEADD + dcol];
    __syncthreads();
    for (int d = quarter; d < 64; d += 4)
        vT[(size_t)(bh * HEADD + d) * CSEQ + c0 + dcol] = t[dcol][d];
}

// ---------------------------------------------------------------------------
// Flash attention v5: R4 structure (4 waves x 16 q-rows, swapped QK^T, P via
// wave-private swizzled LDS, double-buffered global_load_lds staging, 1
// barrier/tile) + fixed-max exp2 softmax (|S|<=8 bound; -8*log2e folded into
// the MFMA C-initializer, 0.125*log2e folded into q). No max-reduce, no
// rescale, no branch, no mrun state.
// ---------------------------------------------------------------------------
#define KVB 64
#define NT  (CSEQ / KVB)
#define C8L2E 11.541560f      // 8 * log2(e)

__global__ __launch_bounds__(256, 4) void attn_kernel(
    const _Float16* __restrict__ qn, const _Float16* __restrict__ kn,
    const _Float16* __restrict__ vT, _Float16* __restrict__ o)
{
    __shared__ _Float16 KsB[2][KVB * 64];
    __shared__ _Float16 VsB[2][KVB * 64];
    __shared__ _Float16 P[4][16 * 64];
    int tid = threadIdx.x, lane = tid & 63, w = tid >> 6;
    int l15 = lane & 15, lg = lane >> 4;

    int orig = blockIdx.x;
    int wg   = (orig & 7) * 128 + (orig >> 3);   // bijective, 1024 = 8*128
    int bh   = wg >> 5;
    int qc   = wg & 31;
    int q0   = qc * 64 + w * 16;

    const _Float16* qh = qn + (size_t)bh * CSEQ * HEADD;
    const _Float16* kh = kn + (size_t)bh * CSEQ * HEADD;
    const _Float16* vh = vT + (size_t)bh * HEADD * CSEQ;

    half8 aq[2];
    #pragma unroll
    for (int ks = 0; ks < 2; ++ks)
        aq[ks] = *(const half8*)&qh[(size_t)(q0 + l15) * HEADD + ks * 32 + lg * 8];

    f32x4 z = {0.f, 0.f, 0.f, 0.f};
    f32x4 oacc[4];
    #pragma unroll
    for (int d4 = 0; d4 < 4; ++d4) oacc[d4] = z;
    float lrun = 0.f;

    int srow_in = lane >> 3;
    int csrc    = (lane & 7) ^ srow_in;
    int lsw     = l15 & 7;

    auto stage = [&](int buf, int kt) {
        int k0 = kt * KVB;
        #pragma unroll
        for (int i = 0; i < 2; ++i) {
            int seg = w * 2 + i;
            int r = seg * 8 + srow_in;
            async16(&KsB[buf][seg * 512], &kh[(size_t)(k0 + r) * HEADD + csrc * 8]);
            async16(&VsB[buf][seg * 512], &vh[(size_t)r * CSEQ + k0 + csrc * 8]);
        }
    };

    stage(0, 0);
    __syncthreads();
    int cur = 0;

    for (int kt = 0; kt < NT; ++kt) {
        if (kt + 1 < NT) stage(cur ^ 1, kt + 1);

        // ---- S^T = K * Q^T, C-init = -8*log2e ----
        f32x4 st[4];
        #pragma unroll
        for (int n = 0; n < 4; ++n) st[n] = f32x4{-C8L2E, -C8L2E, -C8L2E, -C8L2E};
        #pragma unroll
        for (int ks = 0; ks < 2; ++ks) {
            half8 ak[4];
            #pragma unroll
            for (int n = 0; n < 4; ++n) {
                int row = n * 16 + l15;
                int ch = (ks * 4 + lg) ^ (row & 7);
                ak[n] = *(const half8*)&KsB[cur][row * 64 + ch * 8];
            }
            #pragma unroll
            for (int n = 0; n < 4; ++n)
                st[n] = __builtin_amdgcn_mfma_f32_16x16x32_f16(ak[n], aq[ks], st[n], 0, 0, 0);
        }

        // ---- fixed-max softmax: p = exp2(st), no max, no rescale ----
        float ps = 0.f;
        #pragma unroll
        for (int n = 0; n < 4; ++n)
            #pragma unroll
            for (int r = 0; r < 4; ++r) {
                float e = exp2f(st[n][r]);
                st[n][r] = e;
                ps += e;
            }
        ps += __shfl_xor(ps, 16);
        ps += __shfl_xor(ps, 32);
        lrun += ps;

        // ---- P store: transposed layout P[q=l15][k], 16B-chunk XOR swizzle ----
        #pragma unroll
        for (int n = 0; n < 4; ++n) {
            half4v pk;
            #pragma unroll
            for (int r = 0; r < 4; ++r) pk[r] = (_Float16)st[n][r];
            int t  = n * 2 + (lg >> 1);
            int tp = t ^ lsw;
            *(half4v*)&P[w][l15 * 64 + tp * 8 + (lg & 1) * 4] = pk;
        }
        // wave-private P: no barrier needed

        // ---- PV ----
        #pragma unroll
        for (int ks = 0; ks < 2; ++ks) {
            int tp2 = (ks * 4 + lg) ^ lsw;
            half8 ap = *(const half8*)&P[w][l15 * 64 + tp2 * 8];
            half8 bv[4];
            #pragma unroll
            for (int d4 = 0; d4 < 4; ++d4) {
                int row = d4 * 16 + l15;
                int ch = (ks * 4 + lg) ^ (row & 7);
                bv[d4] = *(const half8*)&VsB[cur][row * 64 + ch * 8];
            }
            #pragma unroll
            for (int d4 = 0; d4 < 4; ++d4)
                oacc[d4] = __builtin_amdgcn_mfma_f32_16x16x32_f16(ap, bv[d4], oacc[d4], 0, 0, 0);
        }

        __syncthreads();
        cur ^= 1;
    }

    int b = bh >> 4, h = bh & 15;
    #pragma unroll
    for (int r = 0; r < 4; ++r) {
        float lr = __shfl(lrun, lg * 4 + r);
        float inv = 1.f / lr;
        int c = q0 + lg * 4 + r;
        size_t base = ((size_t)b * CSEQ + c) * D_MODEL + h * HEADD;
        #pragma unroll
        for (int d4 = 0; d4 < 4; ++d4)
            o[base + d4 * 16 + l15] = (_Float16)(oacc[d4][r] * inv);
    }
}

// ---------------------------------------------------------------------------
extern "C" void kernel_launch(void* const* d_in, const int* in_sizes, int n_in,
                              void* d_out, int out_size, void* d_ws, size_t ws_size,
                              hipStream_t stream)
{
    (void)in_sizes; (void)n_in; (void)out_size; (void)ws_size;
    const float* x      = (const float*)d_in[0];
    const float* ln_q_g = (const float*)d_in[1];
    const float* ln_q_b = (const float*)d_in[2];
    const float* Wq     = (const float*)d_in[3];
    const float* bq     = (const float*)d_in[4];
    const float* ln_kv_g= (const float*)d_in[5];
    const float* ln_kv_b= (const float*)d_in[6];
    const float* Wkv    = (const float*)d_in[7];
    const float* bkv    = (const float*)d_in[8];
    const float* Wout   = (const float*)d_in[9];
    const float* bout   = (const float*)d_in[10];
    const float* lnh_g  = (const float*)d_in[11];
    const float* lnh_b  = (const float*)d_in[12];
    const float* Wr     = (const float*)d_in[13];
    const float* br     = (const float*)d_in[14];
    float* out = (float*)d_out;

    char* ws = (char*)d_ws;
    size_t off = 0;
    auto alloc = [&](size_t bytes) -> void* {
        void* p = ws + off;
        off += (bytes + 255) & ~(size_t)255;
        return p;
    };
    _Float16* WqkvT  = (_Float16*)alloc((size_t)NQKV * D_MODEL * 2);
    _Float16* WoutT  = (_Float16*)alloc((size_t)D_MODEL * D_MODEL * 2);
    float*    bias_e = (float*)   alloc((size_t)NQKV * 4);
    float*    radius = (float*)   alloc((size_t)NROWS * 4);
    float2*   cs_tab = (float2*)  alloc((size_t)CSEQ * NFREQ * 8);
    _Float16* vT     = (_Float16*)alloc((size_t)BATCH * NHEADS * HEADD * CSEQ * 2);
    _Float16* v_rm   = (_Float16*)alloc((size_t)NROWS * D_MODEL * 2);
    _Float16* xn     = (_Float16*)alloc((size_t)NROWS * D_MODEL * 2);
    _Float16* qn     = (_Float16*)alloc((size_t)NROWS * D_MODEL * 2);
    _Float16* kn     = (_Float16*)alloc((size_t)NROWS * D_MODEL * 2);
    _Float16* o_h    = (_Float16*)alloc((size_t)NROWS * D_MODEL * 2);

    hipLaunchKernelGGL(bias_init_kernel, dim3(NQKV / 256), dim3(256), 0, stream, bq, bkv, bias_e);
    hipLaunchKernelGGL(build_cs_kernel, dim3(CSEQ * NFREQ / 256), dim3(256), 0, stream, cs_tab);
    hipLaunchKernelGGL(transpose_fold_kernel, dim3(D_MODEL/32, D_MODEL/32), dim3(32, 8), 0, stream,
                       Wq, WqkvT, D_MODEL, D_MODEL, 0, ln_q_g, ln_q_b, bias_e);
    hipLaunchKernelGGL(transpose_fold_kernel, dim3(2*D_MODEL/32, D_MODEL/32), dim3(32, 8), 0, stream,
                       Wkv, WqkvT, D_MODEL, 2*D_MODEL, D_MODEL, ln_kv_g, ln_kv_b, bias_e);
    hipLaunchKernelGGL(transpose_fold_kernel, dim3(D_MODEL/32, D_MODEL/32), dim3(32, 8), 0, stream,
                       Wout, WoutT, D_MODEL, D_MODEL, 0, (const float*)nullptr,
                       (const float*)nullptr, (float*)nullptr);
    hipLaunchKernelGGL(ln_radius_kernel, dim3(NROWS), dim3(256), 0, stream,
                       x, Wr, br, xn, radius);
    hipLaunchKernelGGL(gemm_qkv_kernel, dim3(768), dim3(256), 0, stream,
                       xn, WqkvT, bias_e, radius, cs_tab, lnh_g, lnh_b, qn, kn, v_rm);
    hipLaunchKernelGGL(v_transpose_f16, dim3(BATCH*NHEADS*CSEQ/64), dim3(256), 0, stream,
                       v_rm, vT);
    hipLaunchKernelGGL(attn_kernel, dim3(BATCH*NHEADS*CSEQ/64), dim3(256), 0, stream,
                       qn, kn, vT, o_h);
    hipLaunchKernelGGL(gemm_out_kernel, dim3(256), dim3(256), 0, stream,
                       o_h, WoutT, bout, out);
}